// Round 8
// baseline (296.614 us; speedup 1.0000x reference)
//
#include <hip/hip_runtime.h>

typedef unsigned short u16;
typedef unsigned int   u32;
typedef unsigned long long u64;
typedef short bf16x8 __attribute__((ext_vector_type(8)));
typedef float f32x4  __attribute__((ext_vector_type(4)));
typedef u32   u32x4  __attribute__((ext_vector_type(4)));

#define NA 22       /* agents per graph */
#define FIN 32      /* input feature dim */
#define XS_STR 520  /* xs LDS row stride (u16): 1040B */
#define AL_STR 24   /* alpha row stride (u16): [dst i][src j 0..23], j 22,23 zeroed */

/* d_ws layout (u16): main B-frags then fused-attention (Wav) frags */
#define W1_OFF 0          /* 32 frags   */
#define W2_OFF 16384      /* 512 frags  */
#define W3_OFF 278528     /* 128 frags  */
#define E1_OFF 344064     /* 1 frag     */
#define E2_OFF 344576     /* 16 frags   */
#define E3_OFF 352768     /* 16 frags   */
#define WS_TOTAL 360960

__device__ u16 f2b(float f) {
    unsigned int x = __float_as_uint(f);
    x = (x + 0x7fffu + ((x >> 16) & 1u)) >> 16;  /* round-nearest-even */
    return (u16)x;
}

/* packed f32x2 -> bf16x2, RNE, one VALU op (gfx950 native) */
__device__ __forceinline__ u32 cvtpk(float lo, float hi) {
    u32 r;
    asm("v_cvt_pk_bf16_f32 %0, %1, %2" : "=v"(r) : "v"(lo), "v"(hi));
    return r;
}

/* W [K][N] fp32 -> bf16 B-frag layout, scatter form (coalesced reads) */
__global__ void swizzle_kernel(const float* W1, const float* W2, const float* W3, u16* ws)
{
    int t = blockIdx.x * 256 + threadIdx.x;
    const float* W; int NT, nshift, base, loc;
    if (t < W2_OFF)      { W = W1; NT = 32; nshift = 9; base = W1_OFF; loc = t; }
    else if (t < W3_OFF) { W = W2; NT = 32; nshift = 9; base = W2_OFF; loc = t - W2_OFF; }
    else if (t < E1_OFF) { W = W3; NT = 8;  nshift = 7; base = W3_OFF; loc = t - W3_OFF; }
    else { return; }
    int k = loc >> nshift;
    int n = loc & ((1 << nshift) - 1);
    u16 v = f2b(W[loc]);
    int kt = k >> 5, quad = (k & 31) >> 3, j = k & 7;
    int nt = n >> 4, lm = n & 15;
    int lane = (quad << 4) | lm;
    ws[base + (((kt * NT + nt) << 9) | (lane << 3) | j)] = v;
}

/* Row-cooperative Wav: one wave per weight row (4 rows/wave for W3). */
__global__ void wav_kernel(const float* W1, const float* as1, const float* ad1,
                           const float* W2, const float* as2, const float* ad2,
                           const float* W3, const float* as3, const float* ad3,
                           u16* ws)
{
    int wid = blockIdx.x * 4 + (threadIdx.x >> 6);   /* 672 wave-tasks */
    int lane = threadIdx.x & 63;
    int grp = lane >> 4, c4 = lane & 15;

    if (wid < 544) {                                  /* H=4, N=512 (W1,W2) */
        const float* W; const float* asp; const float* adp; int k, base;
        if (wid < 32) { W = W1; asp = as1; adp = ad1; k = wid;      base = E1_OFF; }
        else          { W = W2; asp = as2; adp = ad2; k = wid - 32; base = E2_OFF; }
        int h = grp;
        const float4* wp = (const float4*)(W + k * 512 + lane * 8);
        float4 wa = wp[0], wb = wp[1];
        const float4* sp = (const float4*)(asp + h * 128 + c4 * 8);
        const float4* dp = (const float4*)(adp + h * 128 + c4 * 8);
        float4 sa = sp[0], sb = sp[1];
        float4 da = dp[0], db = dp[1];
        float ps = wa.x*sa.x + wa.y*sa.y + wa.z*sa.z + wa.w*sa.w
                 + wb.x*sb.x + wb.y*sb.y + wb.z*sb.z + wb.w*sb.w;
        float pd = wa.x*da.x + wa.y*da.y + wa.z*da.z + wa.w*da.w
                 + wb.x*db.x + wb.y*db.y + wb.z*db.z + wb.w*db.w;
        #pragma unroll
        for (int off = 1; off <= 8; off <<= 1) {
            ps += __shfl_xor(ps, off);
            pd += __shfl_xor(pd, off);
        }
        int kt = k >> 5, quad = (k & 31) >> 3, j = k & 7;
        if (c4 < 4) {
            int col = c4 * 4 + h;
            float v = (c4 == 0) ? ps : (c4 == 1) ? pd : 0.0f;
            ws[base + (kt << 9) + (((quad << 4) | col) << 3) + j] = f2b(v);
        }
    } else if (wid < 672) {                           /* W3: H=1, N=128, 4 rows/wave */
        int k = (wid - 544) * 4 + grp;
        const float4* wp = (const float4*)(W3 + k * 128 + c4 * 8);
        float4 wa = wp[0], wb = wp[1];
        const float4* sp = (const float4*)(as3 + c4 * 8);
        const float4* dp = (const float4*)(ad3 + c4 * 8);
        float4 sa = sp[0], sb = sp[1];
        float4 da = dp[0], db = dp[1];
        float ps = wa.x*sa.x + wa.y*sa.y + wa.z*sa.z + wa.w*sa.w
                 + wb.x*sb.x + wb.y*sb.y + wb.z*sb.z + wb.w*sb.w;
        float pd = wa.x*da.x + wa.y*da.y + wa.z*da.z + wa.w*da.w
                 + wb.x*db.x + wb.y*db.y + wb.z*db.z + wb.w*db.w;
        #pragma unroll
        for (int off = 1; off <= 8; off <<= 1) {
            ps += __shfl_xor(ps, off);
            pd += __shfl_xor(pd, off);
        }
        int kt = k >> 5, quad = (k & 31) >> 3, j = k & 7;
        float v = (c4 == 0) ? ps : (c4 == 1) ? pd : 0.0f;
        ws[E3_OFF + (kt << 9) + (((quad << 4) | c4) << 3) + j] = f2b(v);
    }
}

/* leaky-relu + softmax over 22 src nodes; vectorized LDS reads,
   packed b128 al-row writes. */
__device__ __forceinline__ void softmax_al(const float* sw, u16* al_slot, int lane)
{
    if (lane < NA) {
        float di = sw[24 + lane];
        f32x4 c0 = *(const f32x4*)(sw);
        f32x4 c1 = *(const f32x4*)(sw + 4);
        f32x4 c2 = *(const f32x4*)(sw + 8);
        f32x4 c3 = *(const f32x4*)(sw + 12);
        f32x4 c4 = *(const f32x4*)(sw + 16);
        float s20 = sw[20], s21 = sw[21];
        float lg[NA];
        float mx = -1.0e30f, ss = 0.0f;
        #pragma unroll
        for (int j = 0; j < NA; ++j) {
            float sj = (j < 4)  ? c0[j]      : (j < 8)  ? c1[j - 4]  :
                       (j < 12) ? c2[j - 8]  : (j < 16) ? c3[j - 12] :
                       (j < 20) ? c4[j - 16] : (j == 20) ? s20 : s21;
            float l = di + sj;
            l = fmaxf(l, 0.2f * l);                  /* leaky relu 0.2 */
            lg[j] = l;
            mx = fmaxf(mx, l);
        }
        #pragma unroll
        for (int j = 0; j < NA; ++j) {
            float e = __expf(lg[j] - mx);
            lg[j] = e;
            ss += e;
        }
        float inv = 1.0f / ss;
        u32 pk[12];
        #pragma unroll
        for (int j2 = 0; j2 < 11; ++j2) {
            pk[j2] = cvtpk(lg[2 * j2] * inv, lg[2 * j2 + 1] * inv);
        }
        pk[11] = 0;                                  /* zero K-pad cols 22,23 */
        u32* arow = (u32*)(al_slot + lane * AL_STR);
        *(u32x4*)(arow)     = (u32x4){pk[0], pk[1], pk[2],  pk[3]};
        *(u32x4*)(arow + 4) = (u32x4){pk[4], pk[5], pk[6],  pk[7]};
        *(u32x4*)(arow + 8) = (u32x4){pk[8], pk[9], pk[10], pk[11]};
    }
}

/* s/d accumulator -> head-slot sw, vector stores */
__device__ __forceinline__ void store_sd(float* swp, f32x4 e0, f32x4 e1, int quad)
{
    *(f32x4*)(swp + quad * 4) = e0;                  /* rows quad*4..+3 */
    if (quad == 0) { *(f32x4*)(swp + 16) = e1; }     /* rows 16..19 */
    else if (quad == 1) { swp[20] = e1[0]; swp[21] = e1[1]; }  /* rows 20,21 */
}

/* One GAT layer (layers 1,2), 8 waves. Weight frags prefetched DEPTH-3
   (bbuf[3]) to cover L2 latency. Attention coefficients (accE) + softmax
   computed only by EVEN waves (wave 2h owns head h); odd waves read the
   even wave's al slot after the first barrier. Exactly 2 barriers/layer.
   Cross-layer al/svw reuse safety: layer L's aggregate reads al[h] between
   L.bar1 and L.bar2; layer L+1's softmax writes al[h] only after L.bar2. */
template<int KT, int NT, int NTW, int H>
__device__ __forceinline__ void gat_layer(
    const u16* Wsw, const u16* Wext, const float* bias,
    u16* xs, float* svw, u16* al)
{
    int tid  = threadIdx.x;
    int wave = tid >> 6, lane = tid & 63;
    int quad = lane >> 4, lm = lane & 15;
    int r1 = 16 + lm; if (r1 >= NA) { r1 = lm; }   /* dummy valid row */
    int head = (H == 4) ? (wave >> 1) : 0;
    bool doE = (H == 4) ? ((wave & 1) == 0) : (wave == 0);

    f32x4 acc0[NTW], acc1[NTW], accE0, accE1;

    /* ---------- GEMM h = x@W (+ fused s/d columns on owner waves) ---------- */
    {
        const u16* a0base = xs + lm * XS_STR + quad * 8;
        const u16* a1base = xs + r1 * XS_STR + quad * 8;
        const u16* wbase  = Wsw + ((wave * NTW) << 9) + (lane << 3);
        const u16* ebase  = Wext + (lane << 3);

        f32x4 z4 = {0.f, 0.f, 0.f, 0.f};
        #pragma unroll
        for (int n = 0; n < NTW; ++n) { acc0[n] = z4; acc1[n] = z4; }
        accE0 = z4; accE1 = z4;

        bf16x8 bbuf[3][NTW], ebuf[2], ab0[2], ab1[2];
        #pragma unroll
        for (int n = 0; n < NTW; ++n) { bbuf[0][n] = *(const bf16x8*)(wbase + (n << 9)); }
        if (KT > 1) {
            #pragma unroll
            for (int n = 0; n < NTW; ++n) { bbuf[1][n] = *(const bf16x8*)(wbase + ((NT + n) << 9)); }
        }
        if (doE) { ebuf[0] = *(const bf16x8*)(ebase); }
        ab0[0] = *(const bf16x8*)(a0base);
        ab1[0] = *(const bf16x8*)(a1base);

        #pragma unroll
        for (int kt = 0; kt < KT; ++kt) {
            const int c3 = kt % 3;
            const int cA = kt & 1;
            const int nA = cA ^ 1;
            if (kt + 2 < KT) {                       /* depth-3 weight prefetch */
                const int p3 = (kt + 2) % 3;
                const u16* wn = wbase + (((kt + 2) * NT) << 9);
                #pragma unroll
                for (int n = 0; n < NTW; ++n) { bbuf[p3][n] = *(const bf16x8*)(wn + (n << 9)); }
            }
            if (kt + 1 < KT) {                       /* depth-2 A/E prefetch */
                if (doE) { ebuf[nA] = *(const bf16x8*)(ebase + ((kt + 1) << 9)); }
                ab0[nA] = *(const bf16x8*)(a0base + (kt + 1) * 32);
                ab1[nA] = *(const bf16x8*)(a1base + (kt + 1) * 32);
            }
            #pragma unroll
            for (int n = 0; n < NTW; ++n) {
                acc0[n] = __builtin_amdgcn_mfma_f32_16x16x32_bf16(ab0[cA], bbuf[c3][n], acc0[n], 0, 0, 0);
                acc1[n] = __builtin_amdgcn_mfma_f32_16x16x32_bf16(ab1[cA], bbuf[c3][n], acc1[n], 0, 0, 0);
            }
            if (doE) {
                accE0 = __builtin_amdgcn_mfma_f32_16x16x32_bf16(ab0[cA], ebuf[cA], accE0, 0, 0, 0);
                accE1 = __builtin_amdgcn_mfma_f32_16x16x32_bf16(ab1[cA], ebuf[cA], accE1, 0, 0, 0);
            }
        }
    }

    /* ---------- owner wave: s/d -> head slot; softmax -> al[head] ---------- */
    float* sw = svw + head * 48;                 /* [0..23]=s, [24..47]=d */
    if (doE) {
        if (lm == head)     { store_sd(sw,      accE0, accE1, quad); }
        if (lm == head + H) { store_sd(sw + 24, accE0, accE1, quad); }
        softmax_al(sw, al + head * NA * AL_STR, lane);
    }

    /* ---------- in-register transpose acc -> aggregate B-frags (all) ------ */
    bf16x8 bfrag[NTW];
    {
        int s0 = (((quad & 1) << 5) | lm) << 2;   /* byte index for bpermute */
        int s2 = s0 + 64;
        bool hi = (quad >= 2);
        #pragma unroll
        for (int n = 0; n < NTW; ++n) {
            u32 P0a = cvtpk(acc0[n][0], acc0[n][1]);
            u32 P1a = cvtpk(acc0[n][2], acc0[n][3]);
            u32 P0b = cvtpk(acc1[n][0], acc1[n][1]);
            u32 P1b = cvtpk(acc1[n][2], acc1[n][3]);
            u32 w0a = (u32)__builtin_amdgcn_ds_bpermute(s0, (int)P0a);
            u32 w0b = (u32)__builtin_amdgcn_ds_bpermute(s0, (int)P0b);
            u32 w1a = (u32)__builtin_amdgcn_ds_bpermute(s0, (int)P1a);
            u32 w1b = (u32)__builtin_amdgcn_ds_bpermute(s0, (int)P1b);
            u32 w2a = (u32)__builtin_amdgcn_ds_bpermute(s2, (int)P0a);
            u32 w2b = (u32)__builtin_amdgcn_ds_bpermute(s2, (int)P0b);
            u32 w3a = (u32)__builtin_amdgcn_ds_bpermute(s2, (int)P1a);
            /* w3b dead: rows 22,23 killed by zeroed alpha cols / zeroed pa */
            union { u32 w[4]; bf16x8 v; } bu;
            bu.w[0] = hi ? w0b : w0a;
            bu.w[1] = hi ? w1b : w1a;
            bu.w[2] = hi ? w2b : w2a;
            bu.w[3] = hi ? 0u  : w3a;
            bfrag[n] = bu.v;
        }
    }

    __syncthreads();   /* al[head] visible; all waves' GEMM xs-reads done */

    /* ---------- aggregate out = alpha @ h ---------- */
    const u16* albase = al + head * NA * AL_STR;
    bf16x8 zb = {0, 0, 0, 0, 0, 0, 0, 0};
    bf16x8 pa0 = (quad < 3) ? *(const bf16x8*)(albase + lm * AL_STR + quad * 8) : zb;
    bf16x8 pa1 = (quad < 3) ? *(const bf16x8*)(albase + r1 * AL_STR + quad * 8) : zb;

    f32x4 agg0[NTW], agg1[NTW];
    f32x4 z4 = {0.f, 0.f, 0.f, 0.f};
    float bv[NTW];
    #pragma unroll
    for (int n = 0; n < NTW; ++n) {
        int col = (wave * NTW + n) * 16 + lm;
        bv[n] = bias[col];
        agg0[n] = __builtin_amdgcn_mfma_f32_16x16x32_bf16(pa0, bfrag[n], z4, 0, 0, 0);
        agg1[n] = __builtin_amdgcn_mfma_f32_16x16x32_bf16(pa1, bfrag[n], z4, 0, 0, 0);
    }

    #pragma unroll
    for (int n = 0; n < NTW; ++n) {
        int col = (wave * NTW + n) * 16 + lm;
        u16* cbase = xs + col;
        float v0 = fmaxf(agg0[n][0] + bv[n], 0.0f);
        float v1 = fmaxf(agg0[n][1] + bv[n], 0.0f);
        float v2 = fmaxf(agg0[n][2] + bv[n], 0.0f);
        float v3 = fmaxf(agg0[n][3] + bv[n], 0.0f);
        u32 wa0 = cvtpk(v0, v1), wa1 = cvtpk(v2, v3);
        int r0 = quad * 4;
        cbase[(r0 + 0) * XS_STR] = (u16)wa0;
        cbase[(r0 + 1) * XS_STR] = (u16)(wa0 >> 16);
        cbase[(r0 + 2) * XS_STR] = (u16)wa1;
        cbase[(r0 + 3) * XS_STR] = (u16)(wa1 >> 16);
        if (quad < 2) {                              /* rows 16..21 */
            float u0 = fmaxf(agg1[n][0] + bv[n], 0.0f);
            float u1 = fmaxf(agg1[n][1] + bv[n], 0.0f);
            u32 wb0 = cvtpk(u0, u1);
            int r16 = 16 + quad * 4;
            cbase[(r16 + 0) * XS_STR] = (u16)wb0;
            cbase[(r16 + 1) * XS_STR] = (u16)(wb0 >> 16);
            if (quad == 0) {
                float u2 = fmaxf(agg1[n][2] + bv[n], 0.0f);
                float u3 = fmaxf(agg1[n][3] + bv[n], 0.0f);
                u32 wb1 = cvtpk(u2, u3);
                cbase[18 * XS_STR] = (u16)wb1;
                cbase[19 * XS_STR] = (u16)(wb1 >> 16);
            }
        }
    }
    __syncthreads();   /* new xs visible to all waves */
}

/* Final GAT layer (H=1, NTW=1) fused with mean-pool + linear head.
   Only wave 0 computes accE/softmax (head 0); all waves read al slot 0. */
template<int KT, int NT>
__device__ __forceinline__ void gat_final(
    const u16* Wsw, const u16* Wext, const float* bias,
    const u16* xs, float* svw, u16* al,
    const float* Wc, const float* bc, float* partial, float* out, int g)
{
    int tid  = threadIdx.x;
    int wave = tid >> 6, lane = tid & 63;
    int quad = lane >> 4, lm = lane & 15;
    int r1 = 16 + lm; if (r1 >= NA) { r1 = lm; }
    bool doE = (wave == 0);

    f32x4 acc0, acc1, accE0, accE1;

    /* ---------- GEMM (depth-3 weight prefetch) ---------- */
    {
        const u16* a0base = xs + lm * XS_STR + quad * 8;
        const u16* a1base = xs + r1 * XS_STR + quad * 8;
        const u16* wbase  = Wsw + (wave << 9) + (lane << 3);
        const u16* ebase  = Wext + (lane << 3);

        f32x4 z4 = {0.f, 0.f, 0.f, 0.f};
        acc0 = z4; acc1 = z4; accE0 = z4; accE1 = z4;

        bf16x8 bbuf[3], ebuf[2], ab0[2], ab1[2];
        bbuf[0] = *(const bf16x8*)(wbase);
        if (KT > 1) { bbuf[1] = *(const bf16x8*)(wbase + (NT << 9)); }
        if (doE) { ebuf[0] = *(const bf16x8*)(ebase); }
        ab0[0] = *(const bf16x8*)(a0base);
        ab1[0] = *(const bf16x8*)(a1base);

        #pragma unroll
        for (int kt = 0; kt < KT; ++kt) {
            const int c3 = kt % 3;
            const int cA = kt & 1;
            const int nA = cA ^ 1;
            if (kt + 2 < KT) {
                bbuf[(kt + 2) % 3] = *(const bf16x8*)(wbase + (((kt + 2) * NT) << 9));
            }
            if (kt + 1 < KT) {
                if (doE) { ebuf[nA] = *(const bf16x8*)(ebase + ((kt + 1) << 9)); }
                ab0[nA] = *(const bf16x8*)(a0base + (kt + 1) * 32);
                ab1[nA] = *(const bf16x8*)(a1base + (kt + 1) * 32);
            }
            acc0 = __builtin_amdgcn_mfma_f32_16x16x32_bf16(ab0[cA], bbuf[c3], acc0, 0, 0, 0);
            acc1 = __builtin_amdgcn_mfma_f32_16x16x32_bf16(ab1[cA], bbuf[c3], acc1, 0, 0, 0);
            if (doE) {
                accE0 = __builtin_amdgcn_mfma_f32_16x16x32_bf16(ab0[cA], ebuf[cA], accE0, 0, 0, 0);
                accE1 = __builtin_amdgcn_mfma_f32_16x16x32_bf16(ab1[cA], ebuf[cA], accE1, 0, 0, 0);
            }
        }
    }

    /* ---------- wave 0: s/d + softmax into slot 0 ---------- */
    float* sw = svw;
    if (doE) {
        if (lm == 0) { store_sd(sw,      accE0, accE1, quad); }
        if (lm == 1) { store_sd(sw + 24, accE0, accE1, quad); }
        softmax_al(sw, al, lane);
    }

    /* ---------- transpose (all waves) ---------- */
    bf16x8 bfrag;
    {
        int s0 = (((quad & 1) << 5) | lm) << 2;
        int s2 = s0 + 64;
        bool hi = (quad >= 2);
        u32 P0a = cvtpk(acc0[0], acc0[1]);
        u32 P1a = cvtpk(acc0[2], acc0[3]);
        u32 P0b = cvtpk(acc1[0], acc1[1]);
        u32 P1b = cvtpk(acc1[2], acc1[3]);
        u32 w0a = (u32)__builtin_amdgcn_ds_bpermute(s0, (int)P0a);
        u32 w0b = (u32)__builtin_amdgcn_ds_bpermute(s0, (int)P0b);
        u32 w1a = (u32)__builtin_amdgcn_ds_bpermute(s0, (int)P1a);
        u32 w1b = (u32)__builtin_amdgcn_ds_bpermute(s0, (int)P1b);
        u32 w2a = (u32)__builtin_amdgcn_ds_bpermute(s2, (int)P0a);
        u32 w2b = (u32)__builtin_amdgcn_ds_bpermute(s2, (int)P0b);
        u32 w3a = (u32)__builtin_amdgcn_ds_bpermute(s2, (int)P1a);
        union { u32 w[4]; bf16x8 v; } bu;
        bu.w[0] = hi ? w0b : w0a;
        bu.w[1] = hi ? w1b : w1a;
        bu.w[2] = hi ? w2b : w2a;
        bu.w[3] = hi ? 0u  : w3a;
        bfrag = bu.v;
    }

    __syncthreads();   /* al slot 0 visible to all waves */

    /* ---------- aggregate + fused mean-pool + linear ---------- */
    bf16x8 zb = {0, 0, 0, 0, 0, 0, 0, 0};
    bf16x8 pa0 = (quad < 3) ? *(const bf16x8*)(al + lm * AL_STR + quad * 8) : zb;
    bf16x8 pa1 = (quad < 3) ? *(const bf16x8*)(al + r1 * AL_STR + quad * 8) : zb;

    f32x4 z4 = {0.f, 0.f, 0.f, 0.f};
    f32x4 agg0 = __builtin_amdgcn_mfma_f32_16x16x32_bf16(pa0, bfrag, z4, 0, 0, 0);
    f32x4 agg1 = __builtin_amdgcn_mfma_f32_16x16x32_bf16(pa1, bfrag, z4, 0, 0, 0);

    int col = wave * 16 + lm;
    float bvv = bias[col];
    float cs = 0.0f;
    #pragma unroll
    for (int r = 0; r < 4; ++r) { cs += fmaxf(agg0[r] + bvv, 0.0f); }
    #pragma unroll
    for (int r = 0; r < 4; ++r) {
        int row1 = 16 + quad * 4 + r;
        if (row1 < NA) { cs += fmaxf(agg1[r] + bvv, 0.0f); }
    }
    cs += __shfl_xor(cs, 16);
    cs += __shfl_xor(cs, 32);          /* column sum over 22 agents */
    float part = (cs / 22.0f) * Wc[col];
    part += __shfl_xor(part, 1);
    part += __shfl_xor(part, 2);
    part += __shfl_xor(part, 4);
    part += __shfl_xor(part, 8);       /* wave partial over its 16 cols */
    if (lane == 0) { partial[wave] = part; }
    __syncthreads();
    if (tid == 0) {
        float t = 0.0f;
        #pragma unroll
        for (int w = 0; w < 8; ++w) { t += partial[w]; }
        out[g] = t + bc[0];
    }
}

__global__ void __launch_bounds__(512, 3)
pressgnn_kernel(const float* feats, const u16* ws,
                const float* b1, const float* b2, const float* b3,
                const float* Wc, const float* bc,
                float* out)
{
    __shared__ __align__(16) u16 xs[NA * XS_STR];      /* 22880 B */
    __shared__ __align__(16) u16 al[4 * NA * AL_STR];  /*  4224 B (per-head) */
    __shared__ __align__(16) float svw[4 * 48];        /*   768 B (per-head s/d) */
    __shared__ float partial[8];

    int g = blockIdx.x;
    int tid = threadIdx.x;

    /* load this graph's features: fp32 pairs -> packed bf16x2 b32 stores */
    for (int i = tid; i < NA * FIN / 2; i += 512) {
        float2 v = *(const float2*)(feats + g * NA * FIN + i * 2);
        int row = (i * 2) >> 5;
        int c   = (i * 2) & 31;
        *(u32*)(xs + row * XS_STR + c) = cvtpk(v.x, v.y);
    }
    __syncthreads();

    gat_layer<1,  32, 4, 4>(ws + W1_OFF, ws + E1_OFF, b1, xs, svw, al);
    gat_layer<16, 32, 4, 4>(ws + W2_OFF, ws + E2_OFF, b2, xs, svw, al);
    gat_final<16, 8>(ws + W3_OFF, ws + E3_OFF, b3, xs, svw, al,
                     Wc, bc, partial, out, g);
}

extern "C" void kernel_launch(void* const* d_in, const int* in_sizes, int n_in,
                              void* d_out, int out_size, void* d_ws, size_t ws_size,
                              hipStream_t stream) {
    const float* feats = (const float*)d_in[0];
    const float* W1  = (const float*)d_in[1];
    const float* as1 = (const float*)d_in[2];
    const float* ad1 = (const float*)d_in[3];
    const float* b1  = (const float*)d_in[4];
    const float* W2  = (const float*)d_in[5];
    const float* as2 = (const float*)d_in[6];
    const float* ad2 = (const float*)d_in[7];
    const float* b2  = (const float*)d_in[8];
    const float* W3  = (const float*)d_in[9];
    const float* as3 = (const float*)d_in[10];
    const float* ad3 = (const float*)d_in[11];
    const float* b3  = (const float*)d_in[12];
    const float* Wc  = (const float*)d_in[13];
    const float* bc  = (const float*)d_in[14];
    float* out = (float*)d_out;
    u16* ws = (u16*)d_ws;

    /* per-launch weight prep into d_ws (re-poisoned before every call) */
    swizzle_kernel<<<dim3(1344), dim3(256), 0, stream>>>(W1, W2, W3, ws);
    wav_kernel<<<dim3(168), dim3(256), 0, stream>>>(W1, as1, ad1, W2, as2, ad2,
                                                    W3, as3, ad3, ws);

    /* one block per graph; graph count == output element count (B*T = 4096) */
    pressgnn_kernel<<<dim3(out_size), dim3(512), 0, stream>>>(
        feats, ws, b1, b2, b3, Wc, bc, out);
}

// Round 9
// 252.129 us; speedup vs baseline: 1.1764x; 1.1764x over previous
//
#include <hip/hip_runtime.h>

typedef unsigned short u16;
typedef unsigned int   u32;
typedef unsigned long long u64;
typedef short bf16x8 __attribute__((ext_vector_type(8)));
typedef float f32x4  __attribute__((ext_vector_type(4)));
typedef u32   u32x4  __attribute__((ext_vector_type(4)));

#define NA 22       /* agents per graph */
#define FIN 32      /* input feature dim */
#define XS_STR 520  /* xs LDS row stride (u16): 1040B, conflict-free A-frag reads */
#define AL_STR 24   /* alpha row stride (u16): [dst i][src j 0..23], j 22,23 zeroed */

/* d_ws layout (u16): main B-frags then fused-attention (Wav) frags */
#define W1_OFF 0          /* 32 frags   */
#define W2_OFF 16384      /* 512 frags  */
#define W3_OFF 278528     /* 128 frags  */
#define E1_OFF 344064     /* 1 frag     */
#define E2_OFF 344576     /* 16 frags   */
#define E3_OFF 352768     /* 16 frags   */
#define WS_TOTAL 360960

__device__ u16 f2b(float f) {
    unsigned int x = __float_as_uint(f);
    x = (x + 0x7fffu + ((x >> 16) & 1u)) >> 16;  /* round-nearest-even */
    return (u16)x;
}

/* packed f32x2 -> bf16x2, RNE, one VALU op (gfx950 native) */
__device__ __forceinline__ u32 cvtpk(float lo, float hi) {
    u32 r;
    asm("v_cvt_pk_bf16_f32 %0, %1, %2" : "=v"(r) : "v"(lo), "v"(hi));
    return r;
}

/* W [K][N] fp32 -> bf16 B-frag layout, scatter form (coalesced reads):
   element (k,n) -> frag(kt=k/32, nt=n/16), lane=(k%32/8)*16 + n%16, j=k%8 */
__global__ void swizzle_kernel(const float* W1, const float* W2, const float* W3, u16* ws)
{
    int t = blockIdx.x * 256 + threadIdx.x;
    const float* W; int NT, nshift, base, loc;
    if (t < W2_OFF)      { W = W1; NT = 32; nshift = 9; base = W1_OFF; loc = t; }
    else if (t < W3_OFF) { W = W2; NT = 32; nshift = 9; base = W2_OFF; loc = t - W2_OFF; }
    else if (t < E1_OFF) { W = W3; NT = 8;  nshift = 7; base = W3_OFF; loc = t - W3_OFF; }
    else { return; }
    int k = loc >> nshift;
    int n = loc & ((1 << nshift) - 1);
    u16 v = f2b(W[loc]);
    int kt = k >> 5, quad = (k & 31) >> 3, j = k & 7;
    int nt = n >> 4, lm = n & 15;
    int lane = (quad << 4) | lm;
    ws[base + (((kt * NT + nt) << 9) | (lane << 3) | j)] = v;
}

/* Row-cooperative Wav: one wave per weight row (4 rows/wave for W3).
   Lane l holds W[k, l*8 .. l*8+8) (f4x2, coalesced); 16-lane-group shuffle
   reduce, then scatter {s, d, 0, 0} into the E-frag layout.
   Verified correct in rounds 5-8 (absmax unchanged). */
__global__ void wav_kernel(const float* W1, const float* as1, const float* ad1,
                           const float* W2, const float* as2, const float* ad2,
                           const float* W3, const float* as3, const float* ad3,
                           u16* ws)
{
    int wid = blockIdx.x * 4 + (threadIdx.x >> 6);   /* 672 wave-tasks */
    int lane = threadIdx.x & 63;
    int grp = lane >> 4, c4 = lane & 15;

    if (wid < 544) {                                  /* H=4, N=512 (W1,W2) */
        const float* W; const float* asp; const float* adp; int k, base;
        if (wid < 32) { W = W1; asp = as1; adp = ad1; k = wid;      base = E1_OFF; }
        else          { W = W2; asp = as2; adp = ad2; k = wid - 32; base = E2_OFF; }
        int h = grp;
        const float4* wp = (const float4*)(W + k * 512 + lane * 8);
        float4 wa = wp[0], wb = wp[1];
        const float4* sp = (const float4*)(asp + h * 128 + c4 * 8);
        const float4* dp = (const float4*)(adp + h * 128 + c4 * 8);
        float4 sa = sp[0], sb = sp[1];
        float4 da = dp[0], db = dp[1];
        float ps = wa.x*sa.x + wa.y*sa.y + wa.z*sa.z + wa.w*sa.w
                 + wb.x*sb.x + wb.y*sb.y + wb.z*sb.z + wb.w*sb.w;
        float pd = wa.x*da.x + wa.y*da.y + wa.z*da.z + wa.w*da.w
                 + wb.x*db.x + wb.y*db.y + wb.z*db.z + wb.w*db.w;
        #pragma unroll
        for (int off = 1; off <= 8; off <<= 1) {
            ps += __shfl_xor(ps, off);
            pd += __shfl_xor(pd, off);
        }
        int kt = k >> 5, quad = (k & 31) >> 3, j = k & 7;
        if (c4 < 4) {
            int col = c4 * 4 + h;
            float v = (c4 == 0) ? ps : (c4 == 1) ? pd : 0.0f;
            ws[base + (kt << 9) + (((quad << 4) | col) << 3) + j] = f2b(v);
        }
    } else if (wid < 672) {                           /* W3: H=1, N=128, 4 rows/wave */
        int k = (wid - 544) * 4 + grp;
        const float4* wp = (const float4*)(W3 + k * 128 + c4 * 8);
        float4 wa = wp[0], wb = wp[1];
        const float4* sp = (const float4*)(as3 + c4 * 8);
        const float4* dp = (const float4*)(ad3 + c4 * 8);
        float4 sa = sp[0], sb = sp[1];
        float4 da = dp[0], db = dp[1];
        float ps = wa.x*sa.x + wa.y*sa.y + wa.z*sa.z + wa.w*sa.w
                 + wb.x*sb.x + wb.y*sb.y + wb.z*sb.z + wb.w*sb.w;
        float pd = wa.x*da.x + wa.y*da.y + wa.z*da.z + wa.w*da.w
                 + wb.x*db.x + wb.y*db.y + wb.z*db.z + wb.w*db.w;
        #pragma unroll
        for (int off = 1; off <= 8; off <<= 1) {
            ps += __shfl_xor(ps, off);
            pd += __shfl_xor(pd, off);
        }
        int kt = k >> 5, quad = (k & 31) >> 3, j = k & 7;
        float v = (c4 == 0) ? ps : (c4 == 1) ? pd : 0.0f;
        ws[E3_OFF + (kt << 9) + (((quad << 4) | c4) << 3) + j] = f2b(v);
    }
}

/* One GAT layer (layers 1,2), 8 waves, fully wave-local except the two xs
   barriers (round-4 structure: aggregate BEFORE the first barrier). */
template<int KT, int NT, int NTW, int H>
__device__ __forceinline__ void gat_layer(
    const u16* Wsw, const u16* Wext, const float* bias,
    u16* xs, float* svw, u16* al)
{
    int tid  = threadIdx.x;
    int wave = tid >> 6, lane = tid & 63;
    int quad = lane >> 4, lm = lane & 15;
    int r1 = 16 + lm; if (r1 >= NA) { r1 = lm; }   /* dummy valid row */

    f32x4 acc0[NTW], acc1[NTW], accE0, accE1;

    /* ---------- GEMM h = x@W (+ fused s/d columns, every wave) ---------- */
    {
        const u16* a0base = xs + lm * XS_STR + quad * 8;
        const u16* a1base = xs + r1 * XS_STR + quad * 8;
        const u16* wbase  = Wsw + ((wave * NTW) << 9) + (lane << 3);
        const u16* ebase  = Wext + (lane << 3);

        f32x4 z4 = {0.f, 0.f, 0.f, 0.f};
        #pragma unroll
        for (int n = 0; n < NTW; ++n) { acc0[n] = z4; acc1[n] = z4; }
        accE0 = z4; accE1 = z4;

        bf16x8 bbuf[2][NTW], ebuf[2], ab0[2], ab1[2];
        #pragma unroll
        for (int n = 0; n < NTW; ++n) { bbuf[0][n] = *(const bf16x8*)(wbase + (n << 9)); }
        ebuf[0] = *(const bf16x8*)(ebase);
        ab0[0] = *(const bf16x8*)(a0base);
        ab1[0] = *(const bf16x8*)(a1base);

        #pragma unroll
        for (int kt = 0; kt < KT; ++kt) {
            const int cur = kt & 1;
            const int nxt = cur ^ 1;
            if (kt + 1 < KT) {
                const u16* wn = wbase + (((kt + 1) * NT) << 9);
                #pragma unroll
                for (int n = 0; n < NTW; ++n) { bbuf[nxt][n] = *(const bf16x8*)(wn + (n << 9)); }
                ebuf[nxt] = *(const bf16x8*)(ebase + ((kt + 1) << 9));
                ab0[nxt] = *(const bf16x8*)(a0base + (kt + 1) * 32);
                ab1[nxt] = *(const bf16x8*)(a1base + (kt + 1) * 32);
            }
            #pragma unroll
            for (int n = 0; n < NTW; ++n) {
                acc0[n] = __builtin_amdgcn_mfma_f32_16x16x32_bf16(ab0[cur], bbuf[cur][n], acc0[n], 0, 0, 0);
                acc1[n] = __builtin_amdgcn_mfma_f32_16x16x32_bf16(ab1[cur], bbuf[cur][n], acc1[n], 0, 0, 0);
            }
            accE0 = __builtin_amdgcn_mfma_f32_16x16x32_bf16(ab0[cur], ebuf[cur], accE0, 0, 0, 0);
            accE1 = __builtin_amdgcn_mfma_f32_16x16x32_bf16(ab1[cur], ebuf[cur], accE1, 0, 0, 0);
        }
    }

    /* ---------- s/d to wave-private LDS (no barrier: same-wave RAW) ---------- */
    int head = (H == 4) ? (wave >> 1) : 0;
    float* sw = svw + wave * 48;                 /* [0..23]=s, [24..47]=d */
    if (lm == head) {
        #pragma unroll
        for (int r = 0; r < 4; ++r) {
            sw[quad * 4 + r] = accE0[r];
            int row1 = 16 + quad * 4 + r;
            if (row1 < NA) { sw[row1] = accE1[r]; }
        }
    }
    if (lm == head + H) {
        #pragma unroll
        for (int r = 0; r < 4; ++r) {
            sw[24 + quad * 4 + r] = accE0[r];
            int row1 = 16 + quad * 4 + r;
            if (row1 < NA) { sw[24 + row1] = accE1[r]; }
        }
    }

    /* ---------- in-register transpose acc -> aggregate B-frags ---------- */
    bf16x8 bfrag[NTW];
    {
        int s0 = (((quad & 1) << 5) | lm) << 2;   /* byte index for bpermute */
        int s2 = s0 + 64;
        bool hi = (quad >= 2);
        #pragma unroll
        for (int n = 0; n < NTW; ++n) {
            u32 P0a = cvtpk(acc0[n][0], acc0[n][1]);
            u32 P1a = cvtpk(acc0[n][2], acc0[n][3]);
            u32 P0b = cvtpk(acc1[n][0], acc1[n][1]);
            u32 P1b = cvtpk(acc1[n][2], acc1[n][3]);
            u32 w0a = (u32)__builtin_amdgcn_ds_bpermute(s0, (int)P0a);
            u32 w0b = (u32)__builtin_amdgcn_ds_bpermute(s0, (int)P0b);
            u32 w1a = (u32)__builtin_amdgcn_ds_bpermute(s0, (int)P1a);
            u32 w1b = (u32)__builtin_amdgcn_ds_bpermute(s0, (int)P1b);
            u32 w2a = (u32)__builtin_amdgcn_ds_bpermute(s2, (int)P0a);
            u32 w2b = (u32)__builtin_amdgcn_ds_bpermute(s2, (int)P0b);
            u32 w3a = (u32)__builtin_amdgcn_ds_bpermute(s2, (int)P1a);
            /* w3b dead: rows 22,23 killed by zeroed alpha cols / zeroed pa */
            union { u32 w[4]; bf16x8 v; } bu;
            bu.w[0] = hi ? w0b : w0a;
            bu.w[1] = hi ? w1b : w1a;
            bu.w[2] = hi ? w2b : w2a;
            bu.w[3] = hi ? 0u  : w3a;
            bfrag[n] = bu.v;
        }
    }

    /* ---------- per-wave softmax -> alpha (scalar broadcast LDS reads) ----- */
    if (lane < NA) {
        float di = sw[24 + lane];
        float lg[NA];
        float mx = -1.0e30f, ss = 0.0f;
        #pragma unroll
        for (int j = 0; j < NA; ++j) {
            float l = di + sw[j];
            l = fmaxf(l, 0.2f * l);                  /* leaky relu 0.2 */
            lg[j] = l;
            mx = fmaxf(mx, l);
        }
        #pragma unroll
        for (int j = 0; j < NA; ++j) {
            float e = __expf(lg[j] - mx);
            lg[j] = e;
            ss += e;
        }
        float inv = 1.0f / ss;
        u32 pk[12];
        #pragma unroll
        for (int j2 = 0; j2 < 11; ++j2) {
            pk[j2] = cvtpk(lg[2 * j2] * inv, lg[2 * j2 + 1] * inv);
        }
        pk[11] = 0;                                  /* zero K-pad cols 22,23 */
        u32* arow = (u32*)(al + (wave * NA + lane) * AL_STR);
        *(u32x4*)(arow)     = (u32x4){pk[0], pk[1], pk[2],  pk[3]};
        *(u32x4*)(arow + 4) = (u32x4){pk[4], pk[5], pk[6],  pk[7]};
        *(u32x4*)(arow + 8) = (u32x4){pk[8], pk[9], pk[10], pk[11]};
    }

    /* ---------- aggregate out = alpha @ h (all wave-local) ---------- */
    const u16* albase = al + wave * NA * AL_STR;
    bf16x8 zb = {0, 0, 0, 0, 0, 0, 0, 0};
    bf16x8 pa0 = (quad < 3) ? *(const bf16x8*)(albase + lm * AL_STR + quad * 8) : zb;
    bf16x8 pa1 = (quad < 3) ? *(const bf16x8*)(albase + r1 * AL_STR + quad * 8) : zb;

    f32x4 agg0[NTW], agg1[NTW];
    f32x4 z4 = {0.f, 0.f, 0.f, 0.f};
    float bv[NTW];
    #pragma unroll
    for (int n = 0; n < NTW; ++n) {
        int col = (wave * NTW + n) * 16 + lm;
        bv[n] = bias[col];
        agg0[n] = __builtin_amdgcn_mfma_f32_16x16x32_bf16(pa0, bfrag[n], z4, 0, 0, 0);
        agg1[n] = __builtin_amdgcn_mfma_f32_16x16x32_bf16(pa1, bfrag[n], z4, 0, 0, 0);
    }

    __syncthreads();   /* all waves' GEMM xs-reads complete before overwrite */

    #pragma unroll
    for (int n = 0; n < NTW; ++n) {
        int col = (wave * NTW + n) * 16 + lm;
        u16* cbase = xs + col;
        float v0 = fmaxf(agg0[n][0] + bv[n], 0.0f);
        float v1 = fmaxf(agg0[n][1] + bv[n], 0.0f);
        float v2 = fmaxf(agg0[n][2] + bv[n], 0.0f);
        float v3 = fmaxf(agg0[n][3] + bv[n], 0.0f);
        u32 wa0 = cvtpk(v0, v1), wa1 = cvtpk(v2, v3);
        int r0 = quad * 4;
        cbase[(r0 + 0) * XS_STR] = (u16)wa0;
        cbase[(r0 + 1) * XS_STR] = (u16)(wa0 >> 16);
        cbase[(r0 + 2) * XS_STR] = (u16)wa1;
        cbase[(r0 + 3) * XS_STR] = (u16)(wa1 >> 16);
        if (quad < 2) {                              /* rows 16..21 */
            float u0 = fmaxf(agg1[n][0] + bv[n], 0.0f);
            float u1 = fmaxf(agg1[n][1] + bv[n], 0.0f);
            u32 wb0 = cvtpk(u0, u1);
            int r16 = 16 + quad * 4;
            cbase[(r16 + 0) * XS_STR] = (u16)wb0;
            cbase[(r16 + 1) * XS_STR] = (u16)(wb0 >> 16);
            if (quad == 0) {
                float u2 = fmaxf(agg1[n][2] + bv[n], 0.0f);
                float u3 = fmaxf(agg1[n][3] + bv[n], 0.0f);
                u32 wb1 = cvtpk(u2, u3);
                cbase[18 * XS_STR] = (u16)wb1;
                cbase[19 * XS_STR] = (u16)(wb1 >> 16);
            }
        }
    }
    __syncthreads();   /* new xs visible to all waves */
}

/* Final GAT layer (H=1, NTW=1) fused with mean-pool + linear head. */
template<int KT, int NT>
__device__ __forceinline__ void gat_final(
    const u16* Wsw, const u16* Wext, const float* bias,
    const u16* xs, float* svw, u16* al,
    const float* Wc, const float* bc, float* partial, float* out, int g)
{
    int tid  = threadIdx.x;
    int wave = tid >> 6, lane = tid & 63;
    int quad = lane >> 4, lm = lane & 15;
    int r1 = 16 + lm; if (r1 >= NA) { r1 = lm; }

    f32x4 acc0, acc1, accE0, accE1;

    /* ---------- GEMM ---------- */
    {
        const u16* a0base = xs + lm * XS_STR + quad * 8;
        const u16* a1base = xs + r1 * XS_STR + quad * 8;
        const u16* wbase  = Wsw + (wave << 9) + (lane << 3);
        const u16* ebase  = Wext + (lane << 3);

        f32x4 z4 = {0.f, 0.f, 0.f, 0.f};
        acc0 = z4; acc1 = z4; accE0 = z4; accE1 = z4;

        bf16x8 bbuf[2], ebuf[2], ab0[2], ab1[2];
        bbuf[0] = *(const bf16x8*)(wbase);
        ebuf[0] = *(const bf16x8*)(ebase);
        ab0[0] = *(const bf16x8*)(a0base);
        ab1[0] = *(const bf16x8*)(a1base);

        #pragma unroll
        for (int kt = 0; kt < KT; ++kt) {
            const int cur = kt & 1;
            const int nxt = cur ^ 1;
            if (kt + 1 < KT) {
                bbuf[nxt] = *(const bf16x8*)(wbase + (((kt + 1) * NT) << 9));
                ebuf[nxt] = *(const bf16x8*)(ebase + ((kt + 1) << 9));
                ab0[nxt] = *(const bf16x8*)(a0base + (kt + 1) * 32);
                ab1[nxt] = *(const bf16x8*)(a1base + (kt + 1) * 32);
            }
            acc0  = __builtin_amdgcn_mfma_f32_16x16x32_bf16(ab0[cur], bbuf[cur], acc0, 0, 0, 0);
            acc1  = __builtin_amdgcn_mfma_f32_16x16x32_bf16(ab1[cur], bbuf[cur], acc1, 0, 0, 0);
            accE0 = __builtin_amdgcn_mfma_f32_16x16x32_bf16(ab0[cur], ebuf[cur], accE0, 0, 0, 0);
            accE1 = __builtin_amdgcn_mfma_f32_16x16x32_bf16(ab1[cur], ebuf[cur], accE1, 0, 0, 0);
        }
    }

    /* ---------- s/d ---------- */
    float* sw = svw + wave * 48;
    if (lm == 0) {
        #pragma unroll
        for (int r = 0; r < 4; ++r) {
            sw[quad * 4 + r] = accE0[r];
            int row1 = 16 + quad * 4 + r;
            if (row1 < NA) { sw[row1] = accE1[r]; }
        }
    }
    if (lm == 1) {
        #pragma unroll
        for (int r = 0; r < 4; ++r) {
            sw[24 + quad * 4 + r] = accE0[r];
            int row1 = 16 + quad * 4 + r;
            if (row1 < NA) { sw[24 + row1] = accE1[r]; }
        }
    }

    /* ---------- transpose ---------- */
    bf16x8 bfrag;
    {
        int s0 = (((quad & 1) << 5) | lm) << 2;
        int s2 = s0 + 64;
        bool hi = (quad >= 2);
        u32 P0a = cvtpk(acc0[0], acc0[1]);
        u32 P1a = cvtpk(acc0[2], acc0[3]);
        u32 P0b = cvtpk(acc1[0], acc1[1]);
        u32 P1b = cvtpk(acc1[2], acc1[3]);
        u32 w0a = (u32)__builtin_amdgcn_ds_bpermute(s0, (int)P0a);
        u32 w0b = (u32)__builtin_amdgcn_ds_bpermute(s0, (int)P0b);
        u32 w1a = (u32)__builtin_amdgcn_ds_bpermute(s0, (int)P1a);
        u32 w1b = (u32)__builtin_amdgcn_ds_bpermute(s0, (int)P1b);
        u32 w2a = (u32)__builtin_amdgcn_ds_bpermute(s2, (int)P0a);
        u32 w2b = (u32)__builtin_amdgcn_ds_bpermute(s2, (int)P0b);
        u32 w3a = (u32)__builtin_amdgcn_ds_bpermute(s2, (int)P1a);
        union { u32 w[4]; bf16x8 v; } bu;
        bu.w[0] = hi ? w0b : w0a;
        bu.w[1] = hi ? w1b : w1a;
        bu.w[2] = hi ? w2b : w2a;
        bu.w[3] = hi ? 0u  : w3a;
        bfrag = bu.v;
    }

    /* ---------- softmax ---------- */
    if (lane < NA) {
        float di = sw[24 + lane];
        float lg[NA];
        float mx = -1.0e30f, ss = 0.0f;
        #pragma unroll
        for (int j = 0; j < NA; ++j) {
            float l = di + sw[j];
            l = fmaxf(l, 0.2f * l);
            lg[j] = l;
            mx = fmaxf(mx, l);
        }
        #pragma unroll
        for (int j = 0; j < NA; ++j) {
            float e = __expf(lg[j] - mx);
            lg[j] = e;
            ss += e;
        }
        float inv = 1.0f / ss;
        u32 pk[12];
        #pragma unroll
        for (int j2 = 0; j2 < 11; ++j2) {
            pk[j2] = cvtpk(lg[2 * j2] * inv, lg[2 * j2 + 1] * inv);
        }
        pk[11] = 0;
        u32* arow = (u32*)(al + (wave * NA + lane) * AL_STR);
        *(u32x4*)(arow)     = (u32x4){pk[0], pk[1], pk[2],  pk[3]};
        *(u32x4*)(arow + 4) = (u32x4){pk[4], pk[5], pk[6],  pk[7]};
        *(u32x4*)(arow + 8) = (u32x4){pk[8], pk[9], pk[10], pk[11]};
    }

    /* ---------- aggregate + fused mean-pool + linear ---------- */
    const u16* albase = al + wave * NA * AL_STR;
    bf16x8 zb = {0, 0, 0, 0, 0, 0, 0, 0};
    bf16x8 pa0 = (quad < 3) ? *(const bf16x8*)(albase + lm * AL_STR + quad * 8) : zb;
    bf16x8 pa1 = (quad < 3) ? *(const bf16x8*)(albase + r1 * AL_STR + quad * 8) : zb;

    f32x4 z4 = {0.f, 0.f, 0.f, 0.f};
    f32x4 agg0 = __builtin_amdgcn_mfma_f32_16x16x32_bf16(pa0, bfrag, z4, 0, 0, 0);
    f32x4 agg1 = __builtin_amdgcn_mfma_f32_16x16x32_bf16(pa1, bfrag, z4, 0, 0, 0);

    int col = wave * 16 + lm;
    float bvv = bias[col];
    float cs = 0.0f;
    #pragma unroll
    for (int r = 0; r < 4; ++r) { cs += fmaxf(agg0[r] + bvv, 0.0f); }
    #pragma unroll
    for (int r = 0; r < 4; ++r) {
        int row1 = 16 + quad * 4 + r;
        if (row1 < NA) { cs += fmaxf(agg1[r] + bvv, 0.0f); }
    }
    cs += __shfl_xor(cs, 16);
    cs += __shfl_xor(cs, 32);          /* all quads: column sum over 22 agents */
    float part = (cs / 22.0f) * Wc[col];
    part += __shfl_xor(part, 1);
    part += __shfl_xor(part, 2);
    part += __shfl_xor(part, 4);
    part += __shfl_xor(part, 8);       /* wave partial over its 16 cols */
    if (lane == 0) { partial[wave] = part; }
    __syncthreads();
    if (tid == 0) {
        float t = 0.0f;
        #pragma unroll
        for (int w = 0; w < 8; ++w) { t += partial[w]; }
        out[g] = t + bc[0];
    }
}

__global__ void __launch_bounds__(512, 3)
pressgnn_kernel(const float* feats, const u16* ws,
                const float* b1, const float* b2, const float* b3,
                const float* Wc, const float* bc,
                float* out)
{
    __shared__ __align__(16) u16 xs[NA * XS_STR];      /* 22880 B */
    __shared__ __align__(16) u16 al[8 * NA * AL_STR];  /*  8448 B (wave-private) */
    __shared__ __align__(16) float svw[8 * 48];        /*  1536 B (wave-private s/d) */
    __shared__ float partial[8];

    int g = blockIdx.x;
    int tid = threadIdx.x;

    /* load this graph's features: [NA][FIN] fp32 -> bf16 LDS */
    for (int i = tid; i < NA * FIN; i += 512) {
        int row = i >> 5;
        int col = i & 31;
        xs[row * XS_STR + col] = f2b(feats[g * NA * FIN + i]);
    }
    __syncthreads();

    gat_layer<1,  32, 4, 4>(ws + W1_OFF, ws + E1_OFF, b1, xs, svw, al);
    gat_layer<16, 32, 4, 4>(ws + W2_OFF, ws + E2_OFF, b2, xs, svw, al);
    gat_final<16, 8>(ws + W3_OFF, ws + E3_OFF, b3, xs, svw, al,
                     Wc, bc, partial, out, g);
}

extern "C" void kernel_launch(void* const* d_in, const int* in_sizes, int n_in,
                              void* d_out, int out_size, void* d_ws, size_t ws_size,
                              hipStream_t stream) {
    const float* feats = (const float*)d_in[0];
    const float* W1  = (const float*)d_in[1];
    const float* as1 = (const float*)d_in[2];
    const float* ad1 = (const float*)d_in[3];
    const float* b1  = (const float*)d_in[4];
    const float* W2  = (const float*)d_in[5];
    const float* as2 = (const float*)d_in[6];
    const float* ad2 = (const float*)d_in[7];
    const float* b2  = (const float*)d_in[8];
    const float* W3  = (const float*)d_in[9];
    const float* as3 = (const float*)d_in[10];
    const float* ad3 = (const float*)d_in[11];
    const float* b3  = (const float*)d_in[12];
    const float* Wc  = (const float*)d_in[13];
    const float* bc  = (const float*)d_in[14];
    float* out = (float*)d_out;
    u16* ws = (u16*)d_ws;

    /* per-launch weight prep into d_ws (re-poisoned before every call) */
    swizzle_kernel<<<dim3(1344), dim3(256), 0, stream>>>(W1, W2, W3, ws);
    wav_kernel<<<dim3(168), dim3(256), 0, stream>>>(W1, as1, ad1, W2, as2, ad2,
                                                    W3, as3, ad3, ws);

    /* one block per graph; graph count == output element count (B*T = 4096) */
    pressgnn_kernel<<<dim3(out_size), dim3(512), 0, stream>>>(
        feats, ws, b1, b2, b3, Wc, bc, out);
}

// Round 10
// 248.362 us; speedup vs baseline: 1.1943x; 1.0152x over previous
//
#include <hip/hip_runtime.h>

typedef unsigned short u16;
typedef unsigned int   u32;
typedef unsigned long long u64;
typedef short bf16x8 __attribute__((ext_vector_type(8)));
typedef float f32x4  __attribute__((ext_vector_type(4)));
typedef u32   u32x4  __attribute__((ext_vector_type(4)));

#define NA 22       /* agents per graph */
#define FIN 32      /* input feature dim */
#define XS_STR 520  /* xs LDS row stride (u16): 1040B, conflict-free A-frag reads */
#define AL_STR 24   /* alpha row stride (u16): [dst i][src j 0..23], j 22,23 zeroed */

/* d_ws layout (u16): main B-frags then fused-attention (Wav) frags */
#define W1_OFF 0          /* 32 frags   */
#define W2_OFF 16384      /* 512 frags  */
#define W3_OFF 278528     /* 128 frags  */
#define E1_OFF 344064     /* 1 frag     */
#define E2_OFF 344576     /* 16 frags   */
#define E3_OFF 352768     /* 16 frags   */
#define WS_TOTAL 360960

__device__ u16 f2b(float f) {
    unsigned int x = __float_as_uint(f);
    x = (x + 0x7fffu + ((x >> 16) & 1u)) >> 16;  /* round-nearest-even */
    return (u16)x;
}

/* packed f32x2 -> bf16x2, RNE, one VALU op (gfx950 native).
   Bit-identical to f2b pairs on finite values (verified rounds 3-9). */
__device__ __forceinline__ u32 cvtpk(float lo, float hi) {
    u32 r;
    asm("v_cvt_pk_bf16_f32 %0, %1, %2" : "=v"(r) : "v"(lo), "v"(hi));
    return r;
}

/* ---- fused weight prep: swizzle (frag-major, coalesced 16B stores) + wav ----
   Blocks [0,168): swizzle. One thread per frag-row: 8 consecutive k at fixed n
     -> 4 cvtpk + one b128 store (wave stores 1KB contiguous). Reads: 16-lane
     groups load consecutive n (64B segments) at 8 k-rows each.
   Blocks [168,336): row-cooperative Wav (verified rounds 5-9). */
__global__ void prep_kernel(const float* W1, const float* W2, const float* W3,
                            const float* as1, const float* ad1,
                            const float* as2, const float* ad2,
                            const float* as3, const float* ad3, u16* ws)
{
    if (blockIdx.x < 168) {
        int t = blockIdx.x * 256 + threadIdx.x;      /* 43008 frag-rows */
        const float* W; int ntsh, N, base, loc;
        if (t < 2048)       { W = W1; ntsh = 5; N = 512; base = W1_OFF; loc = t; }
        else if (t < 34816) { W = W2; ntsh = 5; N = 512; base = W2_OFF; loc = t - 2048; }
        else                { W = W3; ntsh = 3; N = 128; base = W3_OFF; loc = t - 34816; }
        int frag = loc >> 6, lane = loc & 63;
        int kt = frag >> ntsh, nt = frag & ((1 << ntsh) - 1);
        int quad = lane >> 4, lm = lane & 15;
        int k0 = kt * 32 + quad * 8;
        int n = nt * 16 + lm;
        const float* wp = W + k0 * N + n;
        u32 o0 = cvtpk(wp[0],     wp[N]);
        u32 o1 = cvtpk(wp[2 * N], wp[3 * N]);
        u32 o2 = cvtpk(wp[4 * N], wp[5 * N]);
        u32 o3 = cvtpk(wp[6 * N], wp[7 * N]);
        *(u32x4*)(ws + base + (frag << 9) + (lane << 3)) = (u32x4){o0, o1, o2, o3};
    } else {
        int wid = (blockIdx.x - 168) * 4 + (threadIdx.x >> 6);   /* 672 wave-tasks */
        int lane = threadIdx.x & 63;
        int grp = lane >> 4, c4 = lane & 15;

        if (wid < 544) {                                  /* H=4, N=512 (W1,W2) */
            const float* W; const float* asp; const float* adp; int k, base;
            if (wid < 32) { W = W1; asp = as1; adp = ad1; k = wid;      base = E1_OFF; }
            else          { W = W2; asp = as2; adp = ad2; k = wid - 32; base = E2_OFF; }
            int h = grp;
            const float4* wp = (const float4*)(W + k * 512 + lane * 8);
            float4 wa = wp[0], wb = wp[1];
            const float4* sp = (const float4*)(asp + h * 128 + c4 * 8);
            const float4* dp = (const float4*)(adp + h * 128 + c4 * 8);
            float4 sa = sp[0], sb = sp[1];
            float4 da = dp[0], db = dp[1];
            float ps = wa.x*sa.x + wa.y*sa.y + wa.z*sa.z + wa.w*sa.w
                     + wb.x*sb.x + wb.y*sb.y + wb.z*sb.z + wb.w*sb.w;
            float pd = wa.x*da.x + wa.y*da.y + wa.z*da.z + wa.w*da.w
                     + wb.x*db.x + wb.y*db.y + wb.z*db.z + wb.w*db.w;
            #pragma unroll
            for (int off = 1; off <= 8; off <<= 1) {
                ps += __shfl_xor(ps, off);
                pd += __shfl_xor(pd, off);
            }
            int kt = k >> 5, quad = (k & 31) >> 3, j = k & 7;
            if (c4 < 4) {
                int col = c4 * 4 + h;
                float v = (c4 == 0) ? ps : (c4 == 1) ? pd : 0.0f;
                ws[base + (kt << 9) + (((quad << 4) | col) << 3) + j] = f2b(v);
            }
        } else if (wid < 672) {                           /* W3: H=1, N=128, 4 rows/wave */
            int k = (wid - 544) * 4 + grp;
            const float4* wp = (const float4*)(W3 + k * 128 + c4 * 8);
            float4 wa = wp[0], wb = wp[1];
            const float4* sp = (const float4*)(as3 + c4 * 8);
            const float4* dp = (const float4*)(ad3 + c4 * 8);
            float4 sa = sp[0], sb = sp[1];
            float4 da = dp[0], db = dp[1];
            float ps = wa.x*sa.x + wa.y*sa.y + wa.z*sa.z + wa.w*sa.w
                     + wb.x*sb.x + wb.y*sb.y + wb.z*sb.z + wb.w*sb.w;
            float pd = wa.x*da.x + wa.y*da.y + wa.z*da.z + wa.w*da.w
                     + wb.x*db.x + wb.y*db.y + wb.z*db.z + wb.w*db.w;
            #pragma unroll
            for (int off = 1; off <= 8; off <<= 1) {
                ps += __shfl_xor(ps, off);
                pd += __shfl_xor(pd, off);
            }
            int kt = k >> 5, quad = (k & 31) >> 3, j = k & 7;
            float v = (c4 == 0) ? ps : (c4 == 1) ? pd : 0.0f;
            ws[E3_OFF + (kt << 9) + (((quad << 4) | c4) << 3) + j] = f2b(v);
        }
    }
}

/* One GAT layer (layers 1,2), 8 waves, fully wave-local except the two xs
   barriers (round-4 structure: aggregate BEFORE the first barrier). */
template<int KT, int NT, int NTW, int H>
__device__ __forceinline__ void gat_layer(
    const u16* Wsw, const u16* Wext, const float* bias,
    u16* xs, float* svw, u16* al)
{
    int tid  = threadIdx.x;
    int wave = tid >> 6, lane = tid & 63;
    int quad = lane >> 4, lm = lane & 15;
    int r1 = 16 + lm; if (r1 >= NA) { r1 = lm; }   /* dummy valid row */

    f32x4 acc0[NTW], acc1[NTW], accE0, accE1;

    /* ---------- GEMM h = x@W (+ fused s/d columns, every wave) ---------- */
    {
        const u16* a0base = xs + lm * XS_STR + quad * 8;
        const u16* a1base = xs + r1 * XS_STR + quad * 8;
        const u16* wbase  = Wsw + ((wave * NTW) << 9) + (lane << 3);
        const u16* ebase  = Wext + (lane << 3);

        f32x4 z4 = {0.f, 0.f, 0.f, 0.f};
        #pragma unroll
        for (int n = 0; n < NTW; ++n) { acc0[n] = z4; acc1[n] = z4; }
        accE0 = z4; accE1 = z4;

        bf16x8 bbuf[2][NTW], ebuf[2], ab0[2], ab1[2];
        #pragma unroll
        for (int n = 0; n < NTW; ++n) { bbuf[0][n] = *(const bf16x8*)(wbase + (n << 9)); }
        ebuf[0] = *(const bf16x8*)(ebase);
        ab0[0] = *(const bf16x8*)(a0base);
        ab1[0] = *(const bf16x8*)(a1base);

        #pragma unroll
        for (int kt = 0; kt < KT; ++kt) {
            const int cur = kt & 1;
            const int nxt = cur ^ 1;
            if (kt + 1 < KT) {
                const u16* wn = wbase + (((kt + 1) * NT) << 9);
                #pragma unroll
                for (int n = 0; n < NTW; ++n) { bbuf[nxt][n] = *(const bf16x8*)(wn + (n << 9)); }
                ebuf[nxt] = *(const bf16x8*)(ebase + ((kt + 1) << 9));
                ab0[nxt] = *(const bf16x8*)(a0base + (kt + 1) * 32);
                ab1[nxt] = *(const bf16x8*)(a1base + (kt + 1) * 32);
            }
            #pragma unroll
            for (int n = 0; n < NTW; ++n) {
                acc0[n] = __builtin_amdgcn_mfma_f32_16x16x32_bf16(ab0[cur], bbuf[cur][n], acc0[n], 0, 0, 0);
                acc1[n] = __builtin_amdgcn_mfma_f32_16x16x32_bf16(ab1[cur], bbuf[cur][n], acc1[n], 0, 0, 0);
            }
            accE0 = __builtin_amdgcn_mfma_f32_16x16x32_bf16(ab0[cur], ebuf[cur], accE0, 0, 0, 0);
            accE1 = __builtin_amdgcn_mfma_f32_16x16x32_bf16(ab1[cur], ebuf[cur], accE1, 0, 0, 0);
        }
    }

    /* ---------- s/d to wave-private LDS (no barrier: same-wave RAW) ---------- */
    int head = (H == 4) ? (wave >> 1) : 0;
    float* sw = svw + wave * 48;                 /* [0..23]=s, [24..47]=d */
    if (lm == head) {
        #pragma unroll
        for (int r = 0; r < 4; ++r) {
            sw[quad * 4 + r] = accE0[r];
            int row1 = 16 + quad * 4 + r;
            if (row1 < NA) { sw[row1] = accE1[r]; }
        }
    }
    if (lm == head + H) {
        #pragma unroll
        for (int r = 0; r < 4; ++r) {
            sw[24 + quad * 4 + r] = accE0[r];
            int row1 = 16 + quad * 4 + r;
            if (row1 < NA) { sw[24 + row1] = accE1[r]; }
        }
    }

    /* ---------- in-register transpose acc -> aggregate B-frags ---------- */
    bf16x8 bfrag[NTW];
    {
        int s0 = (((quad & 1) << 5) | lm) << 2;   /* byte index for bpermute */
        int s2 = s0 + 64;
        bool hi = (quad >= 2);
        #pragma unroll
        for (int n = 0; n < NTW; ++n) {
            u32 P0a = cvtpk(acc0[n][0], acc0[n][1]);
            u32 P1a = cvtpk(acc0[n][2], acc0[n][3]);
            u32 P0b = cvtpk(acc1[n][0], acc1[n][1]);
            u32 P1b = cvtpk(acc1[n][2], acc1[n][3]);
            u32 w0a = (u32)__builtin_amdgcn_ds_bpermute(s0, (int)P0a);
            u32 w0b = (u32)__builtin_amdgcn_ds_bpermute(s0, (int)P0b);
            u32 w1a = (u32)__builtin_amdgcn_ds_bpermute(s0, (int)P1a);
            u32 w1b = (u32)__builtin_amdgcn_ds_bpermute(s0, (int)P1b);
            u32 w2a = (u32)__builtin_amdgcn_ds_bpermute(s2, (int)P0a);
            u32 w2b = (u32)__builtin_amdgcn_ds_bpermute(s2, (int)P0b);
            u32 w3a = (u32)__builtin_amdgcn_ds_bpermute(s2, (int)P1a);
            /* w3b dead: rows 22,23 killed by zeroed alpha cols / zeroed pa */
            union { u32 w[4]; bf16x8 v; } bu;
            bu.w[0] = hi ? w0b : w0a;
            bu.w[1] = hi ? w1b : w1a;
            bu.w[2] = hi ? w2b : w2a;
            bu.w[3] = hi ? 0u  : w3a;
            bfrag[n] = bu.v;
        }
    }

    /* ---------- per-wave softmax -> alpha (scalar broadcast LDS reads) ----- */
    if (lane < NA) {
        float di = sw[24 + lane];
        float lg[NA];
        float mx = -1.0e30f, ss = 0.0f;
        #pragma unroll
        for (int j = 0; j < NA; ++j) {
            float l = di + sw[j];
            l = fmaxf(l, 0.2f * l);                  /* leaky relu 0.2 */
            lg[j] = l;
            mx = fmaxf(mx, l);
        }
        #pragma unroll
        for (int j = 0; j < NA; ++j) {
            float e = __expf(lg[j] - mx);
            lg[j] = e;
            ss += e;
        }
        float inv = 1.0f / ss;
        u32 pk[12];
        #pragma unroll
        for (int j2 = 0; j2 < 11; ++j2) {
            pk[j2] = cvtpk(lg[2 * j2] * inv, lg[2 * j2 + 1] * inv);
        }
        pk[11] = 0;                                  /* zero K-pad cols 22,23 */
        u32* arow = (u32*)(al + (wave * NA + lane) * AL_STR);
        *(u32x4*)(arow)     = (u32x4){pk[0], pk[1], pk[2],  pk[3]};
        *(u32x4*)(arow + 4) = (u32x4){pk[4], pk[5], pk[6],  pk[7]};
        *(u32x4*)(arow + 8) = (u32x4){pk[8], pk[9], pk[10], pk[11]};
    }

    /* ---------- aggregate out = alpha @ h (all wave-local) ---------- */
    const u16* albase = al + wave * NA * AL_STR;
    bf16x8 zb = {0, 0, 0, 0, 0, 0, 0, 0};
    bf16x8 pa0 = (quad < 3) ? *(const bf16x8*)(albase + lm * AL_STR + quad * 8) : zb;
    bf16x8 pa1 = (quad < 3) ? *(const bf16x8*)(albase + r1 * AL_STR + quad * 8) : zb;

    f32x4 agg0[NTW], agg1[NTW];
    f32x4 z4 = {0.f, 0.f, 0.f, 0.f};
    float bv[NTW];
    #pragma unroll
    for (int n = 0; n < NTW; ++n) {
        int col = (wave * NTW + n) * 16 + lm;
        bv[n] = bias[col];
        agg0[n] = __builtin_amdgcn_mfma_f32_16x16x32_bf16(pa0, bfrag[n], z4, 0, 0, 0);
        agg1[n] = __builtin_amdgcn_mfma_f32_16x16x32_bf16(pa1, bfrag[n], z4, 0, 0, 0);
    }

    __syncthreads();   /* all waves' GEMM xs-reads complete before overwrite */

    #pragma unroll
    for (int n = 0; n < NTW; ++n) {
        int col = (wave * NTW + n) * 16 + lm;
        u16* cbase = xs + col;
        float v0 = fmaxf(agg0[n][0] + bv[n], 0.0f);
        float v1 = fmaxf(agg0[n][1] + bv[n], 0.0f);
        float v2 = fmaxf(agg0[n][2] + bv[n], 0.0f);
        float v3 = fmaxf(agg0[n][3] + bv[n], 0.0f);
        u32 wa0 = cvtpk(v0, v1), wa1 = cvtpk(v2, v3);
        int r0 = quad * 4;
        cbase[(r0 + 0) * XS_STR] = (u16)wa0;
        cbase[(r0 + 1) * XS_STR] = (u16)(wa0 >> 16);
        cbase[(r0 + 2) * XS_STR] = (u16)wa1;
        cbase[(r0 + 3) * XS_STR] = (u16)(wa1 >> 16);
        if (quad < 2) {                              /* rows 16..21 */
            float u0 = fmaxf(agg1[n][0] + bv[n], 0.0f);
            float u1 = fmaxf(agg1[n][1] + bv[n], 0.0f);
            u32 wb0 = cvtpk(u0, u1);
            int r16 = 16 + quad * 4;
            cbase[(r16 + 0) * XS_STR] = (u16)wb0;
            cbase[(r16 + 1) * XS_STR] = (u16)(wb0 >> 16);
            if (quad == 0) {
                float u2 = fmaxf(agg1[n][2] + bv[n], 0.0f);
                float u3 = fmaxf(agg1[n][3] + bv[n], 0.0f);
                u32 wb1 = cvtpk(u2, u3);
                cbase[18 * XS_STR] = (u16)wb1;
                cbase[19 * XS_STR] = (u16)(wb1 >> 16);
            }
        }
    }
    __syncthreads();   /* new xs visible to all waves */
}

/* Final GAT layer (H=1, NTW=1) fused with mean-pool + linear head. */
template<int KT, int NT>
__device__ __forceinline__ void gat_final(
    const u16* Wsw, const u16* Wext, const float* bias,
    const u16* xs, float* svw, u16* al,
    const float* Wc, const float* bc, float* partial, float* out, int g)
{
    int tid  = threadIdx.x;
    int wave = tid >> 6, lane = tid & 63;
    int quad = lane >> 4, lm = lane & 15;
    int r1 = 16 + lm; if (r1 >= NA) { r1 = lm; }

    f32x4 acc0, acc1, accE0, accE1;

    /* ---------- GEMM ---------- */
    {
        const u16* a0base = xs + lm * XS_STR + quad * 8;
        const u16* a1base = xs + r1 * XS_STR + quad * 8;
        const u16* wbase  = Wsw + (wave << 9) + (lane << 3);
        const u16* ebase  = Wext + (lane << 3);

        f32x4 z4 = {0.f, 0.f, 0.f, 0.f};
        acc0 = z4; acc1 = z4; accE0 = z4; accE1 = z4;

        bf16x8 bbuf[2], ebuf[2], ab0[2], ab1[2];
        bbuf[0] = *(const bf16x8*)(wbase);
        ebuf[0] = *(const bf16x8*)(ebase);
        ab0[0] = *(const bf16x8*)(a0base);
        ab1[0] = *(const bf16x8*)(a1base);

        #pragma unroll
        for (int kt = 0; kt < KT; ++kt) {
            const int cur = kt & 1;
            const int nxt = cur ^ 1;
            if (kt + 1 < KT) {
                bbuf[nxt] = *(const bf16x8*)(wbase + (((kt + 1) * NT) << 9));
                ebuf[nxt] = *(const bf16x8*)(ebase + ((kt + 1) << 9));
                ab0[nxt] = *(const bf16x8*)(a0base + (kt + 1) * 32);
                ab1[nxt] = *(const bf16x8*)(a1base + (kt + 1) * 32);
            }
            acc0  = __builtin_amdgcn_mfma_f32_16x16x32_bf16(ab0[cur], bbuf[cur], acc0, 0, 0, 0);
            acc1  = __builtin_amdgcn_mfma_f32_16x16x32_bf16(ab1[cur], bbuf[cur], acc1, 0, 0, 0);
            accE0 = __builtin_amdgcn_mfma_f32_16x16x32_bf16(ab0[cur], ebuf[cur], accE0, 0, 0, 0);
            accE1 = __builtin_amdgcn_mfma_f32_16x16x32_bf16(ab1[cur], ebuf[cur], accE1, 0, 0, 0);
        }
    }

    /* ---------- s/d ---------- */
    float* sw = svw + wave * 48;
    if (lm == 0) {
        #pragma unroll
        for (int r = 0; r < 4; ++r) {
            sw[quad * 4 + r] = accE0[r];
            int row1 = 16 + quad * 4 + r;
            if (row1 < NA) { sw[row1] = accE1[r]; }
        }
    }
    if (lm == 1) {
        #pragma unroll
        for (int r = 0; r < 4; ++r) {
            sw[24 + quad * 4 + r] = accE0[r];
            int row1 = 16 + quad * 4 + r;
            if (row1 < NA) { sw[24 + row1] = accE1[r]; }
        }
    }

    /* ---------- transpose ---------- */
    bf16x8 bfrag;
    {
        int s0 = (((quad & 1) << 5) | lm) << 2;
        int s2 = s0 + 64;
        bool hi = (quad >= 2);
        u32 P0a = cvtpk(acc0[0], acc0[1]);
        u32 P1a = cvtpk(acc0[2], acc0[3]);
        u32 P0b = cvtpk(acc1[0], acc1[1]);
        u32 P1b = cvtpk(acc1[2], acc1[3]);
        u32 w0a = (u32)__builtin_amdgcn_ds_bpermute(s0, (int)P0a);
        u32 w0b = (u32)__builtin_amdgcn_ds_bpermute(s0, (int)P0b);
        u32 w1a = (u32)__builtin_amdgcn_ds_bpermute(s0, (int)P1a);
        u32 w1b = (u32)__builtin_amdgcn_ds_bpermute(s0, (int)P1b);
        u32 w2a = (u32)__builtin_amdgcn_ds_bpermute(s2, (int)P0a);
        u32 w2b = (u32)__builtin_amdgcn_ds_bpermute(s2, (int)P0b);
        u32 w3a = (u32)__builtin_amdgcn_ds_bpermute(s2, (int)P1a);
        union { u32 w[4]; bf16x8 v; } bu;
        bu.w[0] = hi ? w0b : w0a;
        bu.w[1] = hi ? w1b : w1a;
        bu.w[2] = hi ? w2b : w2a;
        bu.w[3] = hi ? 0u  : w3a;
        bfrag = bu.v;
    }

    /* ---------- softmax ---------- */
    if (lane < NA) {
        float di = sw[24 + lane];
        float lg[NA];
        float mx = -1.0e30f, ss = 0.0f;
        #pragma unroll
        for (int j = 0; j < NA; ++j) {
            float l = di + sw[j];
            l = fmaxf(l, 0.2f * l);
            lg[j] = l;
            mx = fmaxf(mx, l);
        }
        #pragma unroll
        for (int j = 0; j < NA; ++j) {
            float e = __expf(lg[j] - mx);
            lg[j] = e;
            ss += e;
        }
        float inv = 1.0f / ss;
        u32 pk[12];
        #pragma unroll
        for (int j2 = 0; j2 < 11; ++j2) {
            pk[j2] = cvtpk(lg[2 * j2] * inv, lg[2 * j2 + 1] * inv);
        }
        pk[11] = 0;
        u32* arow = (u32*)(al + (wave * NA + lane) * AL_STR);
        *(u32x4*)(arow)     = (u32x4){pk[0], pk[1], pk[2],  pk[3]};
        *(u32x4*)(arow + 4) = (u32x4){pk[4], pk[5], pk[6],  pk[7]};
        *(u32x4*)(arow + 8) = (u32x4){pk[8], pk[9], pk[10], pk[11]};
    }

    /* ---------- aggregate + fused mean-pool + linear ---------- */
    const u16* albase = al + wave * NA * AL_STR;
    bf16x8 zb = {0, 0, 0, 0, 0, 0, 0, 0};
    bf16x8 pa0 = (quad < 3) ? *(const bf16x8*)(albase + lm * AL_STR + quad * 8) : zb;
    bf16x8 pa1 = (quad < 3) ? *(const bf16x8*)(albase + r1 * AL_STR + quad * 8) : zb;

    f32x4 z4 = {0.f, 0.f, 0.f, 0.f};
    f32x4 agg0 = __builtin_amdgcn_mfma_f32_16x16x32_bf16(pa0, bfrag, z4, 0, 0, 0);
    f32x4 agg1 = __builtin_amdgcn_mfma_f32_16x16x32_bf16(pa1, bfrag, z4, 0, 0, 0);

    int col = wave * 16 + lm;
    float bvv = bias[col];
    float cs = 0.0f;
    #pragma unroll
    for (int r = 0; r < 4; ++r) { cs += fmaxf(agg0[r] + bvv, 0.0f); }
    #pragma unroll
    for (int r = 0; r < 4; ++r) {
        int row1 = 16 + quad * 4 + r;
        if (row1 < NA) { cs += fmaxf(agg1[r] + bvv, 0.0f); }
    }
    cs += __shfl_xor(cs, 16);
    cs += __shfl_xor(cs, 32);          /* all quads: column sum over 22 agents */
    float part = (cs / 22.0f) * Wc[col];
    part += __shfl_xor(part, 1);
    part += __shfl_xor(part, 2);
    part += __shfl_xor(part, 4);
    part += __shfl_xor(part, 8);       /* wave partial over its 16 cols */
    if (lane == 0) { partial[wave] = part; }
    __syncthreads();
    if (tid == 0) {
        float t = 0.0f;
        #pragma unroll
        for (int w = 0; w < 8; ++w) { t += partial[w]; }
        out[g] = t + bc[0];
    }
}

__global__ void __launch_bounds__(512, 3)
pressgnn_kernel(const float* feats, const u16* ws,
                const float* b1, const float* b2, const float* b3,
                const float* Wc, const float* bc,
                float* out)
{
    __shared__ __align__(16) u16 xs[NA * XS_STR];      /* 22880 B */
    __shared__ __align__(16) u16 al[8 * NA * AL_STR];  /*  8448 B (wave-private) */
    __shared__ __align__(16) float svw[8 * 48];        /*  1536 B (wave-private s/d) */
    __shared__ float partial[8];

    int g = blockIdx.x;
    int tid = threadIdx.x;

    /* load this graph's features: [NA][FIN] fp32 -> bf16 LDS */
    for (int i = tid; i < NA * FIN; i += 512) {
        int row = i >> 5;
        int col = i & 31;
        xs[row * XS_STR + col] = f2b(feats[g * NA * FIN + i]);
    }
    __syncthreads();

    gat_layer<1,  32, 4, 4>(ws + W1_OFF, ws + E1_OFF, b1, xs, svw, al);
    gat_layer<16, 32, 4, 4>(ws + W2_OFF, ws + E2_OFF, b2, xs, svw, al);
    gat_final<16, 8>(ws + W3_OFF, ws + E3_OFF, b3, xs, svw, al,
                     Wc, bc, partial, out, g);
}

extern "C" void kernel_launch(void* const* d_in, const int* in_sizes, int n_in,
                              void* d_out, int out_size, void* d_ws, size_t ws_size,
                              hipStream_t stream) {
    const float* feats = (const float*)d_in[0];
    const float* W1  = (const float*)d_in[1];
    const float* as1 = (const float*)d_in[2];
    const float* ad1 = (const float*)d_in[3];
    const float* b1  = (const float*)d_in[4];
    const float* W2  = (const float*)d_in[5];
    const float* as2 = (const float*)d_in[6];
    const float* ad2 = (const float*)d_in[7];
    const float* b2  = (const float*)d_in[8];
    const float* W3  = (const float*)d_in[9];
    const float* as3 = (const float*)d_in[10];
    const float* ad3 = (const float*)d_in[11];
    const float* b3  = (const float*)d_in[12];
    const float* Wc  = (const float*)d_in[13];
    const float* bc  = (const float*)d_in[14];
    float* out = (float*)d_out;
    u16* ws = (u16*)d_ws;

    /* single fused weight-prep launch into d_ws (re-poisoned every call):
       blocks [0,168)=frag-major swizzle, [168,336)=row-cooperative wav */
    prep_kernel<<<dim3(336), dim3(256), 0, stream>>>(
        W1, W2, W3, as1, ad1, as2, ad2, as3, ad3, ws);

    /* one block per graph; graph count == output element count (B*T = 4096) */
    pressgnn_kernel<<<dim3(out_size), dim3(512), 0, stream>>>(
        feats, ws, b1, b2, b3, Wc, bc, out);
}